// Round 4
// baseline (388.815 us; speedup 1.0000x reference)
//
#include <hip/hip_runtime.h>

typedef unsigned short u16;
typedef unsigned int   u32;
typedef short bf8v __attribute__((ext_vector_type(8)));   // 8 bf16 as shorts
typedef float f32x4 __attribute__((ext_vector_type(4)));

#define DEV static __device__ __forceinline__
#define MBYTE (1u<<20)

// ---- bf16 helpers (RNE) ----
DEV u16 f2b(float f) {
    u32 u = __builtin_bit_cast(u32, f);
    u32 r = (u + 0x7fffu + ((u >> 16) & 1u)) >> 16;
    return (u16)r;
}
DEV float b2f(u16 s) { return __builtin_bit_cast(float, (u32)s << 16); }
DEV bf8v ld8(const u16* p) { return *reinterpret_cast<const bf8v*>(p); }

// load 8 consecutive elements as bf16, from f32 or bf16 source
DEV bf8v ldelems(const void* X, long idx, int f32f) {
    if (f32f) {
        const float* p = (const float*)X + idx;
        f32x4 a = *(const f32x4*)p;
        f32x4 b = *(const f32x4*)(p + 4);
        bf8v r;
        r[0] = (short)f2b(a[0]); r[1] = (short)f2b(a[1]);
        r[2] = (short)f2b(a[2]); r[3] = (short)f2b(a[3]);
        r[4] = (short)f2b(b[0]); r[5] = (short)f2b(b[1]);
        r[6] = (short)f2b(b[2]); r[7] = (short)f2b(b[3]);
        return r;
    }
    return ld8((const u16*)X + idx);
}

DEV f32x4 mfma_(bf8v a, bf8v b, f32x4 c) {
    return __builtin_amdgcn_mfma_f32_16x16x32_bf16(a, b, c, 0, 0, 0);
}

// ================= dtype sniffer =================
// flags[0]: float inputs are f32 (else bf16). flags[1]: mask is byte-packed (else int32).
__global__ __launch_bounds__(256) void sniffk(const u32* q, const u32* m, int* flags) {
    __shared__ int c1s, c2s;
    int t = threadIdx.x;
    if (t == 0) { c1s = 0; c2s = 0; }
    __syncthreads();
    int c1 = 0, c2 = 0;
    for (int i = t; i < 1024; i += 256) {
        u32 u = q[i];
        int e = (int)((u >> 23) & 0xff);
        if (u == 0u || (e >= 118 && e <= 134)) c1++;   // plausible N(0,1) f32
        if (m[i] > 1u) c2++;                           // >1 impossible for int32 0/1 mask
    }
    atomicAdd(&c1s, c1);
    atomicAdd(&c2s, c2);
    __syncthreads();
    if (t == 0) { flags[0] = (c1s > 512) ? 1 : 0; flags[1] = (c2s > 100) ? 1 : 0; }
}

// ======================= weight transpose (64x64 tiles), dual-dtype src =======================
__global__ __launch_bounds__(256) void tposek(const void* s0, const void* s1,
                                              const void* s2, const void* s3,
                                              u16* d0, u16* d1, u16* d2, u16* d3,
                                              const int* flags) {
    __shared__ u16 tile[64][65];
    int f32f = flags[0];
    int z = blockIdx.z;
    const void* src = z == 0 ? s0 : (z == 1 ? s1 : (z == 2 ? s2 : s3));
    u16*       dst = z == 0 ? d0 : (z == 1 ? d1 : (z == 2 ? d2 : d3));
    int t = threadIdx.x;
    int r0 = blockIdx.y * 64, c0 = blockIdx.x * 64;
#pragma unroll
    for (int i = 0; i < 16; ++i) {
        int u = i * 256 + t;
        int row = u >> 6, col = u & 63;
        long gi = (long)(r0 + row) * 1024 + c0 + col;
        tile[row][col] = f32f ? f2b(((const float*)src)[gi]) : ((const u16*)src)[gi];
    }
    __syncthreads();
#pragma unroll
    for (int i = 0; i < 8; ++i) {
        int u = i * 256 + t;
        int row = u >> 5, col = (u & 31) * 2;
        u32 v = (u32)tile[col][row] | ((u32)tile[col + 1][row] << 16);
        *(u32*)(dst + (long)(c0 + row) * 1024 + r0 + col) = v;
    }
}

// ======================= 128x128 bf16 GEMM, BK=32, reg-staged =======================
// mode 0: scale 0.125, write bf16 (B,H,S,D)   [Q]
// mode 1: write bf16 (B,H,S,D)                [K]
// mode 2: write bf16 (B,H,D,S)                [V^T]
// mode 3: write row-major, dtype per flag     [final out]
__global__ __launch_bounds__(256) void gemm128(
    const void* x0, const void* x1, const void* x2,
    const u16* w0, const u16* w1, const u16* w2,
    const void* b0, const void* b1, const void* b2,
    void* c0, void* c1, void* c2, int mode_base,
    const int* flags, int a_use_flag) {
    __shared__ __align__(16) u16 Al[128 * 32];
    __shared__ __align__(16) u16 Bl[128 * 32];
    int z = blockIdx.z;
    const void* X    = z == 0 ? x0 : (z == 1 ? x1 : x2);
    const u16*  BT   = z == 0 ? w0 : (z == 1 ? w1 : w2);
    const void* bias = z == 0 ? b0 : (z == 1 ? b1 : b2);
    void*       C    = z == 0 ? c0 : (z == 1 ? c1 : c2);
    int mode = mode_base + z;
    int f32m = flags[0];                    // dtype of inputs (bias) and final out
    int f32a = a_use_flag ? f32m : 0;       // dtype of A operand

    int t = threadIdx.x, w = t >> 6, l = t & 63;
    int lr = l & 15, lg = l >> 4;
    int m0 = blockIdx.y * 128, n0 = blockIdx.x * 128;
    int wr = (w >> 1) * 64, wc = (w & 1) * 64;

    int row0 = t >> 2;                      // 0..63
    int colE = (t & 3) * 8;                 // element col within 32-elem K slice

    f32x4 acc[4][4];
    f32x4 zf = {0.f, 0.f, 0.f, 0.f};
#pragma unroll
    for (int mt = 0; mt < 4; ++mt)
#pragma unroll
        for (int nt = 0; nt < 4; ++nt) acc[mt][nt] = zf;

    for (int kk = 0; kk < 32; ++kk) {
        int ke = kk * 32 + colE;
        bf8v va0 = ldelems(X, (long)(m0 + row0) * 1024 + ke, f32a);
        bf8v va1 = ldelems(X, (long)(m0 + 64 + row0) * 1024 + ke, f32a);
        bf8v vb0 = ld8(BT + (long)(n0 + row0) * 1024 + ke);
        bf8v vb1 = ld8(BT + (long)(n0 + 64 + row0) * 1024 + ke);
        __syncthreads();                    // previous iteration's LDS reads done
        *(bf8v*)((char*)Al + row0 * 64 + colE * 2) = va0;
        *(bf8v*)((char*)Al + 4096 + row0 * 64 + colE * 2) = va1;
        *(bf8v*)((char*)Bl + row0 * 64 + colE * 2) = vb0;
        *(bf8v*)((char*)Bl + 4096 + row0 * 64 + colE * 2) = vb1;
        __syncthreads();
        bf8v af[4], bfr[4];
#pragma unroll
        for (int mt = 0; mt < 4; ++mt) af[mt] = ld8(&Al[(wr + mt * 16 + lr) * 32 + lg * 8]);
#pragma unroll
        for (int nt = 0; nt < 4; ++nt) bfr[nt] = ld8(&Bl[(wc + nt * 16 + lr) * 32 + lg * 8]);
#pragma unroll
        for (int mt = 0; mt < 4; ++mt)
#pragma unroll
            for (int nt = 0; nt < 4; ++nt) acc[mt][nt] = mfma_(af[mt], bfr[nt], acc[mt][nt]);
    }

#pragma unroll
    for (int nt = 0; nt < 4; ++nt) {
        int col = n0 + wc + nt * 16 + lr;
        float bv = f32m ? ((const float*)bias)[col] : b2f(((const u16*)bias)[col]);
#pragma unroll
        for (int mt = 0; mt < 4; ++mt) {
#pragma unroll
            for (int r = 0; r < 4; ++r) {
                int m = m0 + wr + mt * 16 + lg * 4 + r;
                float v = acc[mt][nt][r] + bv;
                if (mode == 0) v *= 0.125f;
                if (mode <= 1) {
                    int bb = m >> 10, s = m & 1023, hh = col >> 6, dd = col & 63;
                    ((u16*)C)[(((bb << 4) + hh) * 1024 + s) * 64 + dd] = f2b(v);
                } else if (mode == 2) {
                    int bb = m >> 10, s = m & 1023, hh = col >> 6, dd = col & 63;
                    ((u16*)C)[(((bb << 4) + hh) * 64 + dd) * 1024 + s] = f2b(v);
                } else {
                    long idx = (long)m * 1024 + col;
                    if (f32m) ((float*)C)[idx] = v; else ((u16*)C)[idx] = f2b(v);
                }
            }
        }
    }
}

// ======================= fused relative attention =======================
// grid (16 qblocks, 16 heads, 4 batch), 256 threads (4 waves x 16 q-rows).
// Swapped QK^T: mfma(K, Q) -> lane owns query q = l&15; keys live in D-rows.
__global__ __launch_bounds__(256) void attnk(
    const u16* __restrict__ Qw, const u16* __restrict__ Kw, const u16* __restrict__ Vtw,
    const void* __restrict__ rel, const void* __restrict__ mask,
    u16* __restrict__ ctx, void* __restrict__ dout, const int* __restrict__ flags) {
    __shared__ float qrel_lds[64][80];
    __shared__ __align__(16) u16 P_lds[4][16][40];
    __shared__ __align__(16) u16 arel_lds[4][16][96];
    __shared__ __align__(16) u16 relT_lds[64][96];   // relT[d][r], zero r>=65
    __shared__ __align__(16) u16 rel_lds[65][72];    // rel[r][d]
    __shared__ float linv_lds[64];
    __shared__ int mask_lds[1024];

    int f32f = flags[0], m8 = flags[1];
    float* attnF = (float*)dout + 4194304;
    u16*   attnB = (u16*)dout + 4194304;

    int t = threadIdx.x, w = t >> 6, l = t & 63;
    int lr = l & 15, lg = l >> 4;
    int qb = blockIdx.x, h = blockIdx.y, b = blockIdx.z;
    int q0 = qb * 64;
    const u16* Qh  = Qw  + (((b << 4) + h) << 16);
    const u16* Kh  = Kw  + (((b << 4) + h) << 16);
    const u16* Vth = Vtw + (((b << 4) + h) << 16);

    for (int i = t; i < 1024; i += 256)
        mask_lds[i] = m8 ? (int)((const unsigned char*)mask)[(b << 10) + i]
                         : ((const int*)mask)[(b << 10) + i];
#pragma unroll
    for (int i = 0; i < 12; ++i) ((u32*)&arel_lds[w][0][0])[l + i * 64] = 0;
    for (int i = t; i < 65 * 64; i += 256) {
        int r = i >> 6, d = i & 63;
        u16 v = f32f ? f2b(((const float*)rel)[i]) : ((const u16*)rel)[i];
        rel_lds[r][d] = v;
        relT_lds[d][r] = v;
    }
    for (int i = t; i < 64 * 31; i += 256) relT_lds[i / 31][65 + i % 31] = 0;
    __syncthreads();

    int qg = q0 + w * 16 + lr;          // this lane's query row
    bf8v qf0 = ld8(Qh + qg * 64 + lg * 8);
    bf8v qf1 = ld8(Qh + qg * 64 + 32 + lg * 8);

    // qrel[q][r] = sum_d Qs[q,d] * rel_emb[r,d]  (r = 0..64), via mfma(rel, Q)
#pragma unroll
    for (int rt = 0; rt < 5; ++rt) {
        int rrow = rt * 16 + lr; if (rrow > 64) rrow = 64;
        f32x4 aq = {0.f, 0.f, 0.f, 0.f};
        aq = mfma_(ld8(&rel_lds[rrow][lg * 8]), qf0, aq);
        aq = mfma_(ld8(&rel_lds[rrow][32 + lg * 8]), qf1, aq);
#pragma unroll
        for (int r = 0; r < 4; ++r) qrel_lds[w * 16 + lr][rt * 16 + lg * 4 + r] = aq[r];
    }
    const float* qrow_rel = qrel_lds[w * 16 + lr];

    auto calc_scores = [&](int k0, int sub) -> f32x4 {
        const u16* kp = Kh + (k0 + sub * 16 + lr) * 64;
        f32x4 s_ = {0.f, 0.f, 0.f, 0.f};
        s_ = mfma_(ld8(kp + lg * 8), qf0, s_);
        s_ = mfma_(ld8(kp + 32 + lg * 8), qf1, s_);
#pragma unroll
        for (int r = 0; r < 4; ++r) {
            int key = k0 + sub * 16 + lg * 4 + r;
            int dlt = key - qg;
            int ri = dlt < -32 ? 0 : (dlt > 32 ? 64 : dlt + 32);
            float sv = s_[r] + qrow_rel[ri];
            s_[r] = mask_lds[key] ? -1.0e18f : sv;
        }
        return s_;
    };

    // ---- pass 1: row max + denominator ----
    float m_run = -3.0e38f, l_run = 0.f;
    for (int kc = 0; kc < 32; ++kc) {
        int k0 = kc * 32;
        f32x4 s0 = calc_scores(k0, 0);
        f32x4 s1 = calc_scores(k0, 1);
        float mx = fmaxf(fmaxf(fmaxf(s0[0], s0[1]), fmaxf(s0[2], s0[3])),
                         fmaxf(fmaxf(s1[0], s1[1]), fmaxf(s1[2], s1[3])));
        float nm = fmaxf(m_run, mx);
        float sum = __expf(s0[0] - nm) + __expf(s0[1] - nm) + __expf(s0[2] - nm) + __expf(s0[3] - nm)
                  + __expf(s1[0] - nm) + __expf(s1[1] - nm) + __expf(s1[2] - nm) + __expf(s1[3] - nm);
        l_run = l_run * __expf(m_run - nm) + sum;
        m_run = nm;
    }
#pragma unroll
    for (int off = 16; off <= 32; off <<= 1) {
        float om = __shfl_xor(m_run, off);
        float ol = __shfl_xor(l_run, off);
        float nm = fmaxf(m_run, om);
        l_run = l_run * __expf(m_run - nm) + ol * __expf(om - nm);
        m_run = nm;
    }
    float inv_l = 1.0f / l_run;
    if (lg == 0) linv_lds[w * 16 + lr] = inv_l;

    // ---- pass 2: P, PV, arel buckets, head-0 attn ----
    f32x4 acc[4];
#pragma unroll
    for (int dt = 0; dt < 4; ++dt) acc[dt] = f32x4{0.f, 0.f, 0.f, 0.f};
    float tlo = 0.f, thi = 0.f;

    for (int kc = 0; kc < 32; ++kc) {
        int k0 = kc * 32;
#pragma unroll
        for (int sub = 0; sub < 2; ++sub) {
            f32x4 s_ = calc_scores(k0, sub);
#pragma unroll
            for (int r = 0; r < 4; ++r) {
                int key = k0 + sub * 16 + lg * 4 + r;
                float p = __expf(s_[r] - m_run);
                P_lds[w][lr][sub * 16 + lg * 4 + r] = f2b(p);
                int dlt = key - qg;
                if (dlt > -32 && dlt < 32) arel_lds[w][lr][dlt + 32] = f2b(p);
                else if (dlt <= -32) tlo += p;
                else thi += p;
                if (h == 0) {
                    long ai = (long)((b << 10) + qg) * 1024 + key;
                    if (f32f) attnF[ai] = p * inv_l; else attnB[ai] = f2b(p * inv_l);
                }
            }
        }
        __builtin_amdgcn_sched_barrier(0);
        bf8v pa = ld8(&P_lds[w][lr][lg * 8]);
#pragma unroll
        for (int dt = 0; dt < 4; ++dt) {
            bf8v vb = ld8(Vth + (dt * 16 + lr) * 1024 + k0 + lg * 8);
            acc[dt] = mfma_(pa, vb, acc[dt]);
        }
        __builtin_amdgcn_sched_barrier(0);
    }

    // tails -> arel[0], arel[64]
    tlo += __shfl_xor(tlo, 16); tlo += __shfl_xor(tlo, 32);
    thi += __shfl_xor(thi, 16); thi += __shfl_xor(thi, 32);
    if (lg == 0) { arel_lds[w][lr][0] = f2b(tlo); arel_lds[w][lr][64] = f2b(thi); }
    __builtin_amdgcn_sched_barrier(0);

    // ctx += arel @ rel_emb   (B = relT_lds[d][r], zero-padded to 96)
#pragma unroll
    for (int ks = 0; ks < 3; ++ks) {
        bf8v aa = ld8(&arel_lds[w][lr][ks * 32 + lg * 8]);
#pragma unroll
        for (int dt = 0; dt < 4; ++dt) {
            bf8v rb = ld8(&relT_lds[dt * 16 + lr][ks * 32 + lg * 8]);
            acc[dt] = mfma_(aa, rb, acc[dt]);
        }
    }

    // epilogue: normalize and write ctx (B,S,DM) bf16
#pragma unroll
    for (int dt = 0; dt < 4; ++dt) {
#pragma unroll
        for (int r = 0; r < 4; ++r) {
            int qrow = w * 16 + lg * 4 + r;
            float v = acc[dt][r] * linv_lds[qrow];
            int qgr = q0 + qrow;
            ctx[((b << 10) + qgr) * 1024 + (h << 6) + dt * 16 + lr] = f2b(v);
        }
    }
}

// ======================= launch =======================
extern "C" void kernel_launch(void* const* d_in, const int* in_sizes, int n_in,
                              void* d_out, int out_size, void* d_ws, size_t ws_size,
                              hipStream_t stream) {
    const void* key   = d_in[0];
    const void* value = d_in[1];
    const void* query = d_in[2];
    const void* mask  = d_in[3];
    const void* Wq = d_in[4];  const void* bq = d_in[5];
    const void* Wk = d_in[6];  const void* bk = d_in[7];
    const void* Wv = d_in[8];  const void* bv = d_in[9];
    const void* Wo = d_in[10]; const void* bo = d_in[11];
    const void* rel = d_in[12];

    char* ws = (char*)d_ws;
    u16* WqT  = (u16*)(ws + 0 * MBYTE);
    u16* WkT  = (u16*)(ws + 2 * MBYTE);
    u16* WvT  = (u16*)(ws + 4 * MBYTE);
    u16* WoT  = (u16*)(ws + 6 * MBYTE);
    u16* Qws  = (u16*)(ws + 8 * MBYTE);
    u16* Kws  = (u16*)(ws + 16 * MBYTE);
    u16* Vtws = (u16*)(ws + 24 * MBYTE);
    u16* ctxw = (u16*)(ws + 32 * MBYTE);
    int* flags = (int*)(ws + 40 * MBYTE);

    sniffk<<<dim3(1), 256, 0, stream>>>((const u32*)query, (const u32*)mask, flags);
    tposek<<<dim3(16, 16, 4), 256, 0, stream>>>(Wq, Wk, Wv, Wo, WqT, WkT, WvT, WoT, flags);
    gemm128<<<dim3(8, 32, 3), 256, 0, stream>>>(query, key, value, WqT, WkT, WvT,
                                                bq, bk, bv, Qws, Kws, Vtws, 0, flags, 1);
    attnk<<<dim3(16, 16, 4), 256, 0, stream>>>(Qws, Kws, Vtws, rel, mask, ctxw, d_out, flags);
    gemm128<<<dim3(8, 32, 1), 256, 0, stream>>>(ctxw, ctxw, ctxw, WoT, WoT, WoT,
                                                bo, bo, bo, d_out, d_out, d_out, 3, flags, 0);
}